// Round 8
// baseline (92.574 us; speedup 1.0000x reference)
//
#include <hip/hip_runtime.h>
#include <math.h>

#define V      21841
#define TOPK   250
#define NT     256
#define NWAVE  (NT / 64)
#define CAP    2048
#define TF0    8.0f         // fixed candidate threshold: 250th/21841 of N(0,16) = 9.17 +/- 0.10;
                            // TF0=8.0 -> ~497+/-22 candidates. Exact fallback if out of [TOPK, CAP].

typedef float floatx4 __attribute__((ext_vector_type(4)));

__device__ __forceinline__ float clipf(float v) {
    return fminf(fmaxf(v, -1e15f), 1e15f);
}
// order-preserving float->uint key (ascending uint == ascending float)
__device__ __forceinline__ unsigned enc(float v) {
    unsigned b = __float_as_uint(v);
    return (b & 0x80000000u) ? ~b : (b | 0x80000000u);
}
__device__ __forceinline__ float dec(unsigned k) {
    unsigned b = (k & 0x80000000u) ? (k & 0x7FFFFFFFu) : ~k;
    return __uint_as_float(b);
}

// wave-0 parallel select over a 256-bin LDS histogram (suffix-scan in registers):
// finds largest bin b with suffix_sum(b) >= kr; writes bin and krem.
__device__ __forceinline__ void wave_select256(const unsigned* hist, unsigned kr,
                                               unsigned* sh_bin, unsigned* sh_krem) {
    const int tid = threadIdx.x;
    if (tid < 64) {
        uint4 h = reinterpret_cast<const uint4*>(hist)[tid];
        unsigned lsum = h.x + h.y + h.z + h.w;
        unsigned suf = lsum;
#pragma unroll
        for (int off = 1; off < 64; off <<= 1) {
            unsigned t = __shfl_down(suf, off);
            if (tid + off < 64) suf += t;
        }
        unsigned above = suf - lsum;           // strictly above my 4-bin group
        if (above < kr && suf >= kr) {         // unique crossing lane
            unsigned hb[4] = {h.x, h.y, h.z, h.w};
            unsigned cum = above;
            int q = 3;
            for (; q >= 0; --q) { cum += hb[q]; if (cum >= kr) break; }
            *sh_bin = (unsigned)((tid << 2) + q);
            *sh_krem = kr - (cum - hb[q]);
        }
    }
}

__global__ __launch_bounds__(NT) void lnclamp_fused(const float* __restrict__ in,
                                                    float* __restrict__ out) {
    __shared__ __align__(16) unsigned hist[256];
    __shared__ __align__(16) unsigned cand[CAP];
    __shared__ int cand_cnt;
    __shared__ unsigned sh_bin, sh_krem;
    __shared__ double redS[NWAVE], redS2[NWAVE];
    __shared__ float sh_mean, sh_istd;

    const int row = blockIdx.x, tid = threadIdx.x, lane = tid & 63;
    const float* rp = in + (size_t)row * V;
    float* op = out + (size_t)row * V;

    const int first = (4 - (row & 3)) & 3;   // 16B alignment phase (V % 4 == 1)
    const int nvec = (V - first) >> 2;
    const int tail = first + (nvec << 2);
    const float4* vp = reinterpret_cast<const float4*>(rp + first);
    floatx4* ovp = reinterpret_cast<floatx4*>(op + first);

    if (tid == 0) cand_cnt = 0;
    __syncthreads();

    // ---------- phase A: full scan, one compare/element; atomics on ~2.3% passers ----------
    auto emit = [&](float v) {
        if (v >= TF0) {
            int p = atomicAdd(&cand_cnt, 1);
            if (p < CAP) cand[p] = enc(clipf(v));
        }
    };
    if (tid < first) emit(rp[tid]);
    for (int j = tid; j < nvec; j += NT) {
        float4 v4 = vp[j];
        emit(v4.x); emit(v4.y); emit(v4.z); emit(v4.w);
    }
    for (int i = tail + tid; i < V; i += NT) emit(rp[i]);
    __syncthreads();
    const int ncand = cand_cnt;
    const bool fastok = (ncand >= TOPK) && (ncand <= CAP);

    unsigned T, krem;
    double s = 0.0, s2 = 0.0;
    if (fastok) {
        // exact radix over candidates in LDS
        unsigned prefix = 0, pmask = 0, kr = TOPK;
        for (int level = 0; level < 4; ++level) {
            const int shift = 24 - 8 * level;
            __syncthreads();
            hist[tid] = 0;
            __syncthreads();
            for (int i = tid; i < ncand; i += NT) {
                unsigned k = cand[i];
                if ((k & pmask) == prefix) atomicAdd(&hist[(k >> shift) & 255u], 1u);
            }
            __syncthreads();
            wave_select256(hist, kr, &sh_bin, &sh_krem);
            __syncthreads();
            prefix |= sh_bin << shift;
            pmask |= 255u << shift;
            kr = sh_krem;
        }
        T = prefix; krem = kr;
        for (int i = tid; i < ncand; i += NT) {
            unsigned k = cand[i];
            if (k > T) { double dv = (double)dec(k); s += dv; s2 += dv * dv; }
        }
    } else {
        // exact fallback: 4-pass MSB radix from global (any data distribution)
        unsigned prefix = 0, pmask = 0, kr = TOPK;
        for (int level = 0; level < 4; ++level) {
            const int shift = 24 - 8 * level;
            __syncthreads();
            hist[tid] = 0;
            __syncthreads();
            for (int i = tid; i < V; i += NT) {
                unsigned k = enc(clipf(rp[i]));
                if ((k & pmask) == prefix) atomicAdd(&hist[(k >> shift) & 255u], 1u);
            }
            __syncthreads();
            wave_select256(hist, kr, &sh_bin, &sh_krem);
            __syncthreads();
            prefix |= sh_bin << shift;
            pmask |= 255u << shift;
            kr = sh_krem;
        }
        T = prefix; krem = kr;
        for (int i = tid; i < V; i += NT) {
            float v = clipf(rp[i]);
            if (enc(v) > T) { double dv = v; s += dv; s2 += dv * dv; }
        }
    }

    // block-reduce s, s2
    for (int off = 32; off > 0; off >>= 1) {
        s += __shfl_down(s, off); s2 += __shfl_down(s2, off);
    }
    const int wid = tid >> 6;
    if (lane == 0) { redS[wid] = s; redS2[wid] = s2; }
    __syncthreads();
    if (tid == 0) {
        double S = 0.0, S2 = 0.0;
        for (int w = 0; w < NWAVE; ++w) { S += redS[w]; S2 += redS2[w]; }
        const double vT = (double)dec(T);
        S += (double)krem * vT;
        S2 += (double)krem * vT * vT;
        const double mean = S / (double)TOPK;
        const double var = (S2 - S * S / (double)TOPK) / (double)(TOPK - 1);
        sh_mean = (float)mean;
        sh_istd = (float)(1.0 / sqrt(var + 1e-8));
    }
    __syncthreads();

    // ---------- phase B: streaming map (row is L2/L3-warm from phase A) ----------
    const float istd = sh_istd;
    const float c1 = -sh_mean * istd - 1.0f;   // n = clip(v)*istd + c1
    // GELU tanh-form via exp: g = n*(1-r), r = 1/(1+exp(1.5957691*(n+0.044715*n^3)))
    auto outf = [&](float v) -> float {
        float n = fmaf(clipf(v), istd, c1);
        float t1 = n * n;
        float t3 = fmaf(t1 * n, 0.044715f, n);
        float e = __expf(1.59576912160573f * t3);
        float r = __frcp_rn(1.0f + e);          // 1/(1+e^y) = (1-tanh(y/2))/2
        float w = fmaf(-0.4f, r, 0.4f);         // 0.4*(1-r)
        return n * w;
    };
    if (tid < first) op[tid] = outf(rp[tid]);
    for (int j = tid; j < nvec; j += NT) {
        float4 v4 = vp[j];
        floatx4 o;
        o.x = outf(v4.x);
        o.y = outf(v4.y);
        o.z = outf(v4.z);
        o.w = outf(v4.w);
        __builtin_nontemporal_store(o, &ovp[j]);
    }
    for (int i = tail + tid; i < V; i += NT) op[i] = outf(rp[i]);
}

extern "C" void kernel_launch(void* const* d_in, const int* in_sizes, int n_in,
                              void* d_out, int out_size, void* d_ws, size_t ws_size,
                              hipStream_t stream) {
    const float* in = (const float*)d_in[0];
    float* out = (float*)d_out;
    const int rows = out_size / V;   // 2048
    hipLaunchKernelGGL(lnclamp_fused, dim3(rows), dim3(NT), 0, stream, in, out);
}

// Round 9
// 88.264 us; speedup vs baseline: 1.0488x; 1.0488x over previous
//
#include <hip/hip_runtime.h>
#include <math.h>

#define V      21841
#define TOPK   250
#define NT     256
#define NWAVE  (NT / 64)
#define SEGCAP 512          // per-wave candidate segment (expect ~125 +/- 11 per wave)
#define TF0    8.0f         // fixed candidate threshold: 250th/21841 of N(0,16) = 9.17 +/- 0.10;
                            // TF0=8.0 -> ~497+/-22 candidates total. Fallback if any segment
                            // overflows or total < TOPK (exact for arbitrary data).

typedef float floatx4 __attribute__((ext_vector_type(4)));

__device__ __forceinline__ float clipf(float v) {
    return fminf(fmaxf(v, -1e15f), 1e15f);
}
// order-preserving float->uint key (ascending uint == ascending float)
__device__ __forceinline__ unsigned enc(float v) {
    unsigned b = __float_as_uint(v);
    return (b & 0x80000000u) ? ~b : (b | 0x80000000u);
}
__device__ __forceinline__ float dec(unsigned k) {
    unsigned b = (k & 0x80000000u) ? (k & 0x7FFFFFFFu) : ~k;
    return __uint_as_float(b);
}

// wave-0 parallel select over a 256-bin LDS histogram (suffix-scan in registers):
// finds largest bin b with suffix_sum(b) >= kr; writes bin and krem.
__device__ __forceinline__ void wave_select256(const unsigned* hist, unsigned kr,
                                               unsigned* sh_bin, unsigned* sh_krem) {
    const int tid = threadIdx.x;
    if (tid < 64) {
        uint4 h = reinterpret_cast<const uint4*>(hist)[tid];
        unsigned lsum = h.x + h.y + h.z + h.w;
        unsigned suf = lsum;
#pragma unroll
        for (int off = 1; off < 64; off <<= 1) {
            unsigned t = __shfl_down(suf, off);
            if (tid + off < 64) suf += t;
        }
        unsigned above = suf - lsum;           // strictly above my 4-bin group
        if (above < kr && suf >= kr) {         // unique crossing lane
            unsigned hb[4] = {h.x, h.y, h.z, h.w};
            unsigned cum = above;
            int q = 3;
            for (; q >= 0; --q) { cum += hb[q]; if (cum >= kr) break; }
            *sh_bin = (unsigned)((tid << 2) + q);
            *sh_krem = kr - (cum - hb[q]);
        }
    }
}

__global__ __launch_bounds__(NT) void lnclamp_fused(const float* __restrict__ in,
                                                    float* __restrict__ out) {
    __shared__ __align__(16) unsigned hist[256];
    __shared__ __align__(16) unsigned cand[NWAVE][SEGCAP];
    __shared__ int cnt[NWAVE];
    __shared__ unsigned sh_bin, sh_krem;
    __shared__ double redS[NWAVE], redS2[NWAVE];
    __shared__ float sh_mean, sh_istd;

    const int row = blockIdx.x, tid = threadIdx.x, lane = tid & 63, wid = tid >> 6;
    const float* rp = in + (size_t)row * V;
    float* op = out + (size_t)row * V;

    const int first = (4 - (row & 3)) & 3;   // 16B alignment phase (V % 4 == 1)
    const int nvec = (V - first) >> 2;
    const int tail = first + (nvec << 2);
    const float4* vp = reinterpret_cast<const float4*>(rp + first);
    floatx4* ovp = reinterpret_cast<floatx4*>(op + first);

    if (tid < NWAVE) cnt[tid] = 0;
    __syncthreads();

    // ---------- phase A: full scan; per-wave compaction; batched loads for MLP ----------
    auto emit = [&](float v) {
        if (v >= TF0) {
            int p = atomicAdd(&cnt[wid], 1);
            if (p < SEGCAP) cand[wid][p] = enc(clipf(v));
        }
    };
    auto emit4 = [&](float4 v) { emit(v.x); emit(v.y); emit(v.z); emit(v.w); };

    if (tid < first) emit(rp[tid]);
    {
        int j = tid;
        for (; j + 3 * NT < nvec; j += 4 * NT) {
            float4 a = vp[j];
            float4 b = vp[j + NT];
            float4 c = vp[j + 2 * NT];
            float4 d = vp[j + 3 * NT];
            emit4(a); emit4(b); emit4(c); emit4(d);
        }
        for (; j < nvec; j += NT) emit4(vp[j]);
    }
    for (int i = tail + tid; i < V; i += NT) emit(rp[i]);
    __syncthreads();

    int ncand = 0;
    bool segok = true;
#pragma unroll
    for (int w = 0; w < NWAVE; ++w) {
        ncand += cnt[w];
        segok = segok && (cnt[w] <= SEGCAP);
    }
    const bool fastok = segok && (ncand >= TOPK);

    unsigned T, krem;
    double s = 0.0, s2 = 0.0;
    if (fastok) {
        // exact radix over the 4 candidate segments in LDS
        unsigned prefix = 0, pmask = 0, kr = TOPK;
        for (int level = 0; level < 4; ++level) {
            const int shift = 24 - 8 * level;
            __syncthreads();
            hist[tid] = 0;
            __syncthreads();
#pragma unroll
            for (int w = 0; w < NWAVE; ++w) {
                for (int i = tid; i < cnt[w]; i += NT) {
                    unsigned k = cand[w][i];
                    if ((k & pmask) == prefix) atomicAdd(&hist[(k >> shift) & 255u], 1u);
                }
            }
            __syncthreads();
            wave_select256(hist, kr, &sh_bin, &sh_krem);
            __syncthreads();
            prefix |= sh_bin << shift;
            pmask |= 255u << shift;
            kr = sh_krem;
        }
        T = prefix; krem = kr;
#pragma unroll
        for (int w = 0; w < NWAVE; ++w) {
            for (int i = tid; i < cnt[w]; i += NT) {
                unsigned k = cand[w][i];
                if (k > T) { double dv = (double)dec(k); s += dv; s2 += dv * dv; }
            }
        }
    } else {
        // exact fallback: 4-pass MSB radix from global (any data distribution)
        unsigned prefix = 0, pmask = 0, kr = TOPK;
        for (int level = 0; level < 4; ++level) {
            const int shift = 24 - 8 * level;
            __syncthreads();
            hist[tid] = 0;
            __syncthreads();
            for (int i = tid; i < V; i += NT) {
                unsigned k = enc(clipf(rp[i]));
                if ((k & pmask) == prefix) atomicAdd(&hist[(k >> shift) & 255u], 1u);
            }
            __syncthreads();
            wave_select256(hist, kr, &sh_bin, &sh_krem);
            __syncthreads();
            prefix |= sh_bin << shift;
            pmask |= 255u << shift;
            kr = sh_krem;
        }
        T = prefix; krem = kr;
        for (int i = tid; i < V; i += NT) {
            float v = clipf(rp[i]);
            if (enc(v) > T) { double dv = v; s += dv; s2 += dv * dv; }
        }
    }

    // block-reduce s, s2
    for (int off = 32; off > 0; off >>= 1) {
        s += __shfl_down(s, off); s2 += __shfl_down(s2, off);
    }
    if (lane == 0) { redS[wid] = s; redS2[wid] = s2; }
    __syncthreads();
    if (tid == 0) {
        double S = 0.0, S2 = 0.0;
        for (int w = 0; w < NWAVE; ++w) { S += redS[w]; S2 += redS2[w]; }
        const double vT = (double)dec(T);
        S += (double)krem * vT;
        S2 += (double)krem * vT * vT;
        const double mean = S / (double)TOPK;
        const double var = (S2 - S * S / (double)TOPK) / (double)(TOPK - 1);
        sh_mean = (float)mean;
        sh_istd = (float)(1.0 / sqrt(var + 1e-8));
    }
    __syncthreads();

    // ---------- phase B: streaming map, unroll 2 (row is L2/L3-warm) ----------
    const float istd = sh_istd;
    const float c1 = -sh_mean * istd - 1.0f;   // n = clip(v)*istd + c1
    // GELU tanh-form via exp: g = n*(1-r), r = 1/(1+exp(1.5957691*(n+0.044715*n^3)))
    auto outf = [&](float v) -> float {
        float n = fmaf(clipf(v), istd, c1);
        float t1 = n * n;
        float t3 = fmaf(t1 * n, 0.044715f, n);
        float e = __expf(1.59576912160573f * t3);
        float r = __frcp_rn(1.0f + e);          // 1/(1+e^y) = (1-tanh(y/2))/2
        float w = fmaf(-0.4f, r, 0.4f);         // 0.4*(1-r)
        return n * w;
    };
    auto map4 = [&](float4 v) -> floatx4 {
        floatx4 o;
        o.x = outf(v.x); o.y = outf(v.y); o.z = outf(v.z); o.w = outf(v.w);
        return o;
    };
    if (tid < first) op[tid] = outf(rp[tid]);
    {
        int j = tid;
        for (; j + NT < nvec; j += 2 * NT) {
            float4 a = vp[j];
            float4 b = vp[j + NT];
            floatx4 oa = map4(a);
            floatx4 ob = map4(b);
            __builtin_nontemporal_store(oa, &ovp[j]);
            __builtin_nontemporal_store(ob, &ovp[j + NT]);
        }
        if (j < nvec) __builtin_nontemporal_store(map4(vp[j]), &ovp[j]);
    }
    for (int i = tail + tid; i < V; i += NT) op[i] = outf(rp[i]);
}

extern "C" void kernel_launch(void* const* d_in, const int* in_sizes, int n_in,
                              void* d_out, int out_size, void* d_ws, size_t ws_size,
                              hipStream_t stream) {
    const float* in = (const float*)d_in[0];
    float* out = (float*)d_out;
    const int rows = out_size / V;   // 2048
    hipLaunchKernelGGL(lnclamp_fused, dim3(rows), dim3(NT), 0, stream, in, out);
}

// Round 10
// 80.179 us; speedup vs baseline: 1.1546x; 1.1008x over previous
//
#include <hip/hip_runtime.h>
#include <math.h>

#define V      21841
#define TOPK   250
#define NT     256
#define NWAVE  (NT / 64)
#define NR     22           // ceil(5460 float4 / 256 threads)
#define SEGCAP 512          // per-wave candidate segment (expect ~125 +/- 11 per wave)
#define TF0    8.0f         // fixed candidate threshold: 250th/21841 of N(0,16) = 9.17 +/- 0.10;
                            // TF0=8.0 -> ~497+/-22 candidates total. Fallback if any segment
                            // overflows or total < TOPK (exact for arbitrary data).

typedef float floatx4 __attribute__((ext_vector_type(4)));

__device__ __forceinline__ float clipf(float v) {
    return fminf(fmaxf(v, -1e15f), 1e15f);
}
// order-preserving float->uint key (ascending uint == ascending float)
__device__ __forceinline__ unsigned enc(float v) {
    unsigned b = __float_as_uint(v);
    return (b & 0x80000000u) ? ~b : (b | 0x80000000u);
}
__device__ __forceinline__ float dec(unsigned k) {
    unsigned b = (k & 0x80000000u) ? (k & 0x7FFFFFFFu) : ~k;
    return __uint_as_float(b);
}

// wave-0 parallel select over a 256-bin LDS histogram (suffix-scan in registers):
// finds largest bin b with suffix_sum(b) >= kr; writes bin and krem.
__device__ __forceinline__ void wave_select256(const unsigned* hist, unsigned kr,
                                               unsigned* sh_bin, unsigned* sh_krem) {
    const int tid = threadIdx.x;
    if (tid < 64) {
        uint4 h = reinterpret_cast<const uint4*>(hist)[tid];
        unsigned lsum = h.x + h.y + h.z + h.w;
        unsigned suf = lsum;
#pragma unroll
        for (int off = 1; off < 64; off <<= 1) {
            unsigned t = __shfl_down(suf, off);
            if (tid + off < 64) suf += t;
        }
        unsigned above = suf - lsum;           // strictly above my 4-bin group
        if (above < kr && suf >= kr) {         // unique crossing lane
            unsigned hb[4] = {h.x, h.y, h.z, h.w};
            unsigned cum = above;
            int q = 3;
            for (; q >= 0; --q) { cum += hb[q]; if (cum >= kr) break; }
            *sh_bin = (unsigned)((tid << 2) + q);
            *sh_krem = kr - (cum - hb[q]);
        }
    }
}

__global__ __launch_bounds__(NT, 4) void lnclamp_fused(const float* __restrict__ in,
                                                       float* __restrict__ out) {
    __shared__ __align__(16) unsigned hist[256];
    __shared__ __align__(16) unsigned cand[NWAVE][SEGCAP];
    __shared__ int cnt[NWAVE];
    __shared__ unsigned sh_bin, sh_krem;
    __shared__ double redS[NWAVE], redS2[NWAVE];
    __shared__ float sh_mean, sh_istd;

    const int row = blockIdx.x, tid = threadIdx.x, lane = tid & 63, wid = tid >> 6;
    const float* rp = in + (size_t)row * V;
    float* op = out + (size_t)row * V;

    const int first = (4 - (row & 3)) & 3;   // 16B alignment phase (V % 4 == 1)
    const int nvec = (V - first) >> 2;
    const int tail = first + (nvec << 2);
    const floatx4* vp = reinterpret_cast<const floatx4*>(rp + first);
    floatx4* ovp = reinterpret_cast<floatx4*>(op + first);

    // ---------- phase A1: load entire row into registers, once (nt: nothing re-reads) ----------
    floatx4 r[NR];
#pragma unroll
    for (int q = 0; q < NR; ++q) {
        int j = tid + q * NT;
        if (j < nvec) r[q] = __builtin_nontemporal_load(vp + j);
    }
    float hv = (tid < first) ? rp[tid] : 0.0f;       // head (<=3 elems)
    const int ti = tail + tid;
    float tv = (ti < V) ? rp[ti] : 0.0f;             // tail (<=3 elems)

    if (tid < NWAVE) cnt[tid] = 0;
    __syncthreads();

    // ---------- phase A2: emit candidates from registers ----------
    auto emit = [&](float v) {
        if (v >= TF0) {
            int p = atomicAdd(&cnt[wid], 1);
            if (p < SEGCAP) cand[wid][p] = enc(clipf(v));
        }
    };
    if (tid < first) emit(hv);
#pragma unroll
    for (int q = 0; q < NR; ++q) {
        int j = tid + q * NT;
        if (j < nvec) { emit(r[q].x); emit(r[q].y); emit(r[q].z); emit(r[q].w); }
    }
    if (ti < V) emit(tv);
    __syncthreads();

    int ncand = 0;
    bool segok = true;
#pragma unroll
    for (int w = 0; w < NWAVE; ++w) {
        ncand += cnt[w];
        segok = segok && (cnt[w] <= SEGCAP);
    }
    const bool fastok = segok && (ncand >= TOPK);

    unsigned T, krem;
    double s = 0.0, s2 = 0.0;
    if (fastok) {
        // exact radix over the candidate segments in LDS
        unsigned prefix = 0, pmask = 0, kr = TOPK;
        for (int level = 0; level < 4; ++level) {
            const int shift = 24 - 8 * level;
            __syncthreads();
            hist[tid] = 0;
            __syncthreads();
#pragma unroll
            for (int w = 0; w < NWAVE; ++w) {
                for (int i = tid; i < cnt[w]; i += NT) {
                    unsigned k = cand[w][i];
                    if ((k & pmask) == prefix) atomicAdd(&hist[(k >> shift) & 255u], 1u);
                }
            }
            __syncthreads();
            wave_select256(hist, kr, &sh_bin, &sh_krem);
            __syncthreads();
            prefix |= sh_bin << shift;
            pmask |= 255u << shift;
            kr = sh_krem;
        }
        T = prefix; krem = kr;
#pragma unroll
        for (int w = 0; w < NWAVE; ++w) {
            for (int i = tid; i < cnt[w]; i += NT) {
                unsigned k = cand[w][i];
                if (k > T) { double dv = (double)dec(k); s += dv; s2 += dv * dv; }
            }
        }
    } else {
        // exact fallback: 4-pass MSB radix from global (any data distribution)
        unsigned prefix = 0, pmask = 0, kr = TOPK;
        for (int level = 0; level < 4; ++level) {
            const int shift = 24 - 8 * level;
            __syncthreads();
            hist[tid] = 0;
            __syncthreads();
            for (int i = tid; i < V; i += NT) {
                unsigned k = enc(clipf(rp[i]));
                if ((k & pmask) == prefix) atomicAdd(&hist[(k >> shift) & 255u], 1u);
            }
            __syncthreads();
            wave_select256(hist, kr, &sh_bin, &sh_krem);
            __syncthreads();
            prefix |= sh_bin << shift;
            pmask |= 255u << shift;
            kr = sh_krem;
        }
        T = prefix; krem = kr;
        for (int i = tid; i < V; i += NT) {
            float v = clipf(rp[i]);
            if (enc(v) > T) { double dv = v; s += dv; s2 += dv * dv; }
        }
    }

    // block-reduce s, s2
    for (int off = 32; off > 0; off >>= 1) {
        s += __shfl_down(s, off); s2 += __shfl_down(s2, off);
    }
    if (lane == 0) { redS[wid] = s; redS2[wid] = s2; }
    __syncthreads();
    if (tid == 0) {
        double S = 0.0, S2 = 0.0;
        for (int w = 0; w < NWAVE; ++w) { S += redS[w]; S2 += redS2[w]; }
        const double vT = (double)dec(T);
        S += (double)krem * vT;
        S2 += (double)krem * vT * vT;
        const double mean = S / (double)TOPK;
        const double var = (S2 - S * S / (double)TOPK) / (double)(TOPK - 1);
        sh_mean = (float)mean;
        sh_istd = (float)(1.0 / sqrt(var + 1e-8));
    }
    __syncthreads();

    // ---------- phase B: map from registers, pure-write stream ----------
    const float istd = sh_istd;
    const float c1 = -sh_mean * istd - 1.0f;   // n = clip(v)*istd + c1
    // GELU tanh-form via exp: g = n*(1-r2), r2 = 1/(1+exp(1.5957691*(n+0.044715*n^3)))
    auto outf = [&](float v) -> float {
        float n = fmaf(clipf(v), istd, c1);
        float t1 = n * n;
        float t3 = fmaf(t1 * n, 0.044715f, n);
        float e = __expf(1.59576912160573f * t3);
        float r2 = __frcp_rn(1.0f + e);         // 1/(1+e^y) = (1-tanh(y/2))/2
        float w = fmaf(-0.4f, r2, 0.4f);        // 0.4*(1-r2)
        return n * w;
    };
    if (tid < first) op[tid] = outf(hv);
#pragma unroll
    for (int q = 0; q < NR; ++q) {
        int j = tid + q * NT;
        if (j < nvec) {
            floatx4 o;
            o.x = outf(r[q].x);
            o.y = outf(r[q].y);
            o.z = outf(r[q].z);
            o.w = outf(r[q].w);
            __builtin_nontemporal_store(o, ovp + j);
        }
    }
    if (ti < V) op[ti] = outf(tv);
}

extern "C" void kernel_launch(void* const* d_in, const int* in_sizes, int n_in,
                              void* d_out, int out_size, void* d_ws, size_t ws_size,
                              hipStream_t stream) {
    const float* in = (const float*)d_in[0];
    float* out = (float*)d_out;
    const int rows = out_size / V;   // 2048
    hipLaunchKernelGGL(lnclamp_fused, dim3(rows), dim3(NT), 0, stream, in, out);
}